// Round 15
// baseline (449.860 us; speedup 1.0000x reference)
//
#include <hip/hip_runtime.h>
#include <cstdint>

typedef unsigned short u16;
typedef short bf16x8 __attribute__((ext_vector_type(8)));
typedef unsigned short u16x8 __attribute__((ext_vector_type(8)));
typedef float f32x4 __attribute__((ext_vector_type(4)));

__device__ __forceinline__ u16 f2bf(float f) {
  union { float f; uint32_t u; } v; v.f = f;
  uint32_t r = (v.u + 0x7fffu + ((v.u >> 16) & 1u)) >> 16;
  return (u16)r;
}

__device__ __forceinline__ void gload_lds16(const u16* g, u16* l) {
  __builtin_amdgcn_global_load_lds(
      (const __attribute__((address_space(1))) void*)g,
      (__attribute__((address_space(3))) void*)l, 16, 0, 0);
}

// ---------------- LayerNorm body: fp32 in -> bf16 out, C = 1024 ----------------
__device__ __forceinline__ void ln_body(const float* __restrict__ x,
                                        u16* __restrict__ h, int row) {
  const int tid = threadIdx.x;
  const float4 v = *reinterpret_cast<const float4*>(x + (long)row * 1024 + tid * 4);
  float s  = v.x + v.y + v.z + v.w;
  float ss = v.x * v.x + v.y * v.y + v.z * v.z + v.w * v.w;
#pragma unroll
  for (int off = 32; off >= 1; off >>= 1) {
    s  += __shfl_xor(s, off, 64);
    ss += __shfl_xor(ss, off, 64);
  }
  __shared__ float red[8];
  const int wave = tid >> 6, lane = tid & 63;
  if (lane == 0) { red[wave] = s; red[4 + wave] = ss; }
  __syncthreads();
  s  = red[0] + red[1] + red[2] + red[3];
  ss = red[4] + red[5] + red[6] + red[7];
  const float mu   = s * (1.0f / 1024.0f);
  const float var  = ss * (1.0f / 1024.0f) - mu * mu;
  const float rstd = rsqrtf(var + 1e-6f);
  ushort4 o;
  o.x = f2bf((v.x - mu) * rstd);
  o.y = f2bf((v.y - mu) * rstd);
  o.z = f2bf((v.z - mu) * rstd);
  o.w = f2bf((v.w - mu) * rstd);
  *reinterpret_cast<ushort4*>(h + (long)row * 1024 + tid * 4) = o;
}

__global__ __launch_bounds__(256) void ln_kernel(const float* __restrict__ x,
                                                 u16* __restrict__ h) {
  ln_body(x, h, blockIdx.x);
}

// ------------- weight transpose+convert body: W[K][N] fp32 -> Wt[N][K] bf16 ----------
struct WEnt { const float* W; u16* Wt; int K, N, tEnd; };
struct WEnts { WEnt e[4]; int n; };

__device__ __forceinline__ void wconv_body(const WEnts& args, int t) {
  __shared__ u16 tile[64][72];
  int i = 0, tStart = 0;
  while (i < args.n - 1 && t >= args.e[i].tEnd) { tStart = args.e[i].tEnd; i++; }
  const float* W = args.e[i].W;
  u16* Wt = args.e[i].Wt;
  const int K = args.e[i].K, N = args.e[i].N;
  const int rel = t - tStart;
  const int ntn = N >> 6;
  const int tn = rel % ntn, tk = rel / ntn;
  const int n0 = tn * 64, k0 = tk * 64;

  const int th = threadIdx.x;
  const int c4 = (th & 15) * 4;
  const int r  = th >> 4;
#pragma unroll
  for (int ii = 0; ii < 4; ii++) {
    const int row = ii * 16 + r;
    const float4 v = *reinterpret_cast<const float4*>(W + (long)(k0 + row) * N + n0 + c4);
    tile[c4 + 0][row] = f2bf(v.x);
    tile[c4 + 1][row] = f2bf(v.y);
    tile[c4 + 2][row] = f2bf(v.z);
    tile[c4 + 3][row] = f2bf(v.w);
  }
  __syncthreads();
  const int c8 = (th & 7) * 8;
  const int rn = th >> 3;
#pragma unroll
  for (int ii = 0; ii < 2; ii++) {
    const int row = ii * 32 + rn;
    *reinterpret_cast<u16x8*>(Wt + (long)(n0 + row) * K + k0 + c8) =
        *reinterpret_cast<const u16x8*>(&tile[row][c8]);
  }
}

__global__ __launch_bounds__(256) void wconvert_all(WEnts args) {
  wconv_body(args, blockIdx.x);
}

// ---- combo: ln rows [0,nLn) + weight-convert tiles [nLn, nLn+tiles) in one grid ----
__global__ __launch_bounds__(256) void ln_wconv_combo(const float* __restrict__ x,
                                                      u16* __restrict__ h, int nLn,
                                                      WEnts args) {
  if ((int)blockIdx.x < nLn) ln_body(x, h, blockIdx.x);
  else                       wconv_body(args, blockIdx.x - nLn);
}

// ---- combo: weight-convert tiles [0,nW) + fp32->bf16 blocks [nW, ...) -------------
__global__ __launch_bounds__(256) void wconv_f2bf_combo(WEnts args, int nW,
                                                        const float* __restrict__ in,
                                                        u16* __restrict__ out) {
  if ((int)blockIdx.x < nW) {
    wconv_body(args, blockIdx.x);
  } else {
    const long i = ((long)(blockIdx.x - nW) * 256 + threadIdx.x) * 4;
    const float4 v = *reinterpret_cast<const float4*>(in + i);
    ushort4 o;
    o.x = f2bf(v.x); o.y = f2bf(v.y); o.z = f2bf(v.z); o.w = f2bf(v.w);
    *reinterpret_cast<ushort4*>(out + i) = o;
  }
}

// ------- V transpose (coalesced LDS-tile): V[b][n][..h*64+d] -> Vt[(b*16+h)][d][nk] ----
__global__ __launch_bounds__(256) void vtrans(const u16* __restrict__ V,
                                              u16* __restrict__ Vt,
                                              int vStride, long vBatch, int nk) {
  __shared__ u16 tile[64][72];
  const int t = threadIdx.x;
  const int b = blockIdx.z, h = blockIdx.y, n0 = blockIdx.x * 64;
  const u16* vp = V + (long)b * vBatch + h * 64;
  u16* op = Vt + (long)(b * 16 + h) * 64 * (long)nk + n0;
  const int ch = t & 7;
#pragma unroll
  for (int i = 0; i < 2; i++) {
    const int n = (t >> 3) + i * 32;
    const u16x8 v = *reinterpret_cast<const u16x8*>(vp + (long)(n0 + n) * vStride + ch * 8);
#pragma unroll
    for (int j = 0; j < 8; j++) tile[ch * 8 + j][n] = v[j];
  }
  __syncthreads();
#pragma unroll
  for (int i = 0; i < 2; i++) {
    const int d = (t >> 3) + i * 32;
    *reinterpret_cast<u16x8*>(op + (long)d * nk + ch * 8) =
        *reinterpret_cast<const u16x8*>(&tile[d][ch * 8]);
  }
}

// ------- GEMM core BK=64: 2-buffer dbuf prefetch; TN in {64,128} ----------------------
// (unchanged R12/R14 structure — see comments there)
template <int TN, bool OUT_BF16, bool GELU_ACT, bool RES>
__device__ __forceinline__ void gemm_core(
    const u16* __restrict__ A, const u16* __restrict__ Bt,
    const float* __restrict__ bias, const float* __restrict__ res,
    void* __restrict__ Cout, int Ndim, int Kdim, int m0, int n0,
    u16* Al, u16* Bl, int qcols, float qscale) {
  constexpr int NF = TN / 32;
  constexpr int ABUF = 128 * 64;   // u16 per A buffer
  constexpr int BBUF = TN * 64;
  const int tid  = threadIdx.x;
  const int lane = tid & 63, wave = tid >> 6;
  const int quad = lane >> 4, l15 = lane & 15;
  const int wr = wave >> 1, wc = wave & 1;

  f32x4 acc[4][NF];
  const f32x4 vzero = {0.f, 0.f, 0.f, 0.f};
#pragma unroll
  for (int i = 0; i < 4; i++)
#pragma unroll
    for (int jj = 0; jj < NF; jj++) acc[i][jj] = vzero;

  const int srcRow = lane >> 3;
  const int srcG   = ((lane & 7) ^ (srcRow & 7)) * 8;
  const u16* gA = A  + (long)(m0 + srcRow) * Kdim + srcG;
  const u16* gB = Bt + (long)(n0 + srcRow) * Kdim + srcG;

  auto stage = [&](int k0, int p) {
#pragma unroll
    for (int i = 0; i < 4; i++)
      gload_lds16(gA + (long)(wave * 32 + i * 8) * Kdim + k0,
                  Al + p * ABUF + wave * 2048 + i * 512);
#pragma unroll
    for (int i = 0; i < TN / 32; i++)
      gload_lds16(gB + (long)(wave * (TN / 4) + i * 8) * Kdim + k0,
                  Bl + p * BBUF + wave * (TN * 16) + i * 512);
  };

  const int off0 = (quad ^ (l15 & 7)) * 8;

  stage(0, 0);
  int p = 0;
  for (int k0 = 0; k0 < Kdim; k0 += 64, p ^= 1) {
    __syncthreads();
    bf16x8 af[2][4], bfr[2][NF];
    const u16* ab = Al + p * ABUF;
    const u16* bb = Bl + p * BBUF;
#pragma unroll
    for (int mt = 0; mt < 4; mt++) {
      const int r = (wr * 64 + mt * 16 + l15) * 64;
      af[0][mt] = *reinterpret_cast<const bf16x8*>(ab + r + off0);
      af[1][mt] = *reinterpret_cast<const bf16x8*>(ab + r + (off0 ^ 32));
    }
#pragma unroll
    for (int nt = 0; nt < NF; nt++) {
      const int r = (wc * (NF * 16) + nt * 16 + l15) * 64;
      bfr[0][nt] = *reinterpret_cast<const bf16x8*>(bb + r + off0);
      bfr[1][nt] = *reinterpret_cast<const bf16x8*>(bb + r + (off0 ^ 32));
    }
    if (k0 + 64 < Kdim) stage(k0 + 64, p ^ 1);
#pragma unroll
    for (int s = 0; s < 2; s++)
#pragma unroll
      for (int mt = 0; mt < 4; mt++)
#pragma unroll
        for (int nt = 0; nt < NF; nt++)
          acc[mt][nt] = __builtin_amdgcn_mfma_f32_16x16x32_bf16(af[s][mt], bfr[s][nt], acc[mt][nt], 0, 0, 0);
  }

#pragma unroll
  for (int nt = 0; nt < NF; nt++) {
    const int col = n0 + wc * (NF * 16) + nt * 16 + l15;
    const float bv = bias[col];
    const float cs = (col < qcols) ? qscale : 1.0f;
#pragma unroll
    for (int mt = 0; mt < 4; mt++) {
#pragma unroll
      for (int r = 0; r < 4; r++) {
        const int row = m0 + wr * 64 + mt * 16 + quad * 4 + r;
        float y = (acc[mt][nt][r] + bv) * cs;
        if (GELU_ACT) {
          const float t = 0.7978845608028654f * (y + 0.044715f * y * y * y);
          y = y / (1.0f + __builtin_amdgcn_exp2f(-2.885390081777927f * t));
        }
        if (RES) y += res[(long)row * Ndim + col];
        if (OUT_BF16)
          ((u16*)Cout)[(long)row * Ndim + col] = f2bf(y);
        else
          ((float*)Cout)[(long)row * Ndim + col] = y;
      }
    }
  }
}

// standalone GEMM kernel (XCD-swizzled block decode); TM=128 fixed
template <int TN, int SX, bool OUT_BF16, bool GELU_ACT, bool RES>
__global__ __launch_bounds__(256, 2) void gemm_bt(
    const u16* __restrict__ A, const u16* __restrict__ Bt,
    const float* __restrict__ bias, const float* __restrict__ res,
    void* __restrict__ Cout, int Ndim, int Kdim, int lx, int ly,
    int qcols, float qscale) {
  __shared__ u16 Al[2 * 128 * 64];
  __shared__ u16 Bl[2 * TN * 64];
  const int j = blockIdx.x;
  const int c = j & 7, kk = j >> 3;
  const int cx = c % SX, cy = c / SX;
  const int bx = cx * lx + (kk % lx);
  const int by = cy * ly + (kk / lx);
  gemm_core<TN, OUT_BF16, GELU_ACT, RES>(
      A, Bt, bias, res, Cout, Ndim, Kdim, by * 128, bx * TN, Al, Bl, qcols, qscale);
}

// dual-segment GEMM: two independent bf16-out GEMMs in one grid (one dispatch).
struct GemmSeg {
  const u16* A; const u16* Bt; const float* bias; u16* C;
  int Ndim, Kdim, SX, lx, ly, qcols; float qscale;
};
struct GemmDualP { GemmSeg s0, s1; int nBlk0; };

template <int TN>
__global__ __launch_bounds__(256, 2) void gemm_dual(GemmDualP pp) {
  __shared__ u16 Al[2 * 128 * 64];
  __shared__ u16 Bl[2 * TN * 64];
  int j = blockIdx.x;
  GemmSeg s;
  if (j < pp.nBlk0) { s = pp.s0; } else { s = pp.s1; j -= pp.nBlk0; }
  const int c = j & 7, kk = j >> 3;
  const int cx = c % s.SX, cy = c / s.SX;
  const int bx = cx * s.lx + (kk % s.lx);
  const int by = cy * s.ly + (kk / s.lx);
  gemm_core<TN, true, false, false>(
      s.A, s.Bt, s.bias, nullptr, s.C, s.Ndim, s.Kdim, by * 128, bx * TN, Al, Bl,
      s.qcols, s.qscale);
}

// ------- W2 GEMM: wave-split-K, barrier-free main loop (anti-convoy) ------------------
// 4 waves each own K/4 and compute a FULL 64x64 fp32 partial with a WAVE-PRIVATE
// double-buffered LDS pipeline: no __syncthreads in the main loop; each wave paces
// itself with s_waitcnt vmcnt(8) (8 gloads = one step always in flight, never 0).
// This removes the per-window all-wave barrier drain that capped the 2-phase core at
// ~27% MfmaUtil on this K=4096 dispatch.  Partials reduce through LDS at the end.
//
// LDS 64 KB (2 blk/CU = 2 independent waves per SIMD).  Staging layout per wave:
// [64 rows][32 u16] with R1-proven swizzle: phys granule g of row r holds global
// granule g ^ ((r>>1)&3); staged via per-lane source granule (lane&3)^((lane>>3)&3)
// (gload dest LINEAR); frag reads use (quad ^ ((l15>>1)&3)) — zero conflicts.
// stage(s+2) is issued AFTER the MFMAs: frag regs are lgkm-waited by then, so the
// returning gload (>=200cy later) cannot clobber unread LDS.
// Reduction map (verified): owner lane L, slot (mt,nt,r) <-> row m0+mt*16+(L>>4)*4+r,
// col n0+nt*16+(L&15).  Reducing wave w, lane l handles L = w*16+(l>>2), mt = l&3.
__global__ __launch_bounds__(256, 2) void gemm_wsk(
    const u16* __restrict__ A, const u16* __restrict__ Bt,
    const float* __restrict__ bias, const float* __restrict__ res,
    float* __restrict__ Cout, int Ndim, int Kdim) {
  __shared__ u16 lds[2 * 4 * 2 * 2048];   // 64 KB: A half [0,16K) u16, B half [16K,32K)
  u16* Albase = lds;
  u16* Blbase = lds + 4 * 2 * 2048;

  const int tid = threadIdx.x;
  const int lane = tid & 63, wave = tid >> 6;
  const int quad = lane >> 4, l15 = lane & 15;

  const int j = blockIdx.x;
  const int c = j & 7, kk = j >> 3;
  const int bx = (c & 1) * 8 + (kk & 7);       // 16 col-tiles
  const int by = (c >> 1) * 16 + (kk >> 3);    // 64 row-tiles
  const int m0 = by * 64, n0 = bx * 64;

  f32x4 acc[4][4];
  const f32x4 vzero = {0.f, 0.f, 0.f, 0.f};
#pragma unroll
  for (int i = 0; i < 4; i++)
#pragma unroll
    for (int jj = 0; jj < 4; jj++) acc[i][jj] = vzero;

  const int kbase = wave * (Kdim >> 2);
  // lane i stages row (i>>2), phys granule (i&3) holding global granule (i&3)^((i>>3)&3)
  const long rowOff = (long)(lane >> 2) * Kdim + (((lane & 3) ^ ((lane >> 3) & 3)) * 8);
  const u16* gA = A  + (long)m0 * Kdim + rowOff + kbase;
  const u16* gB = Bt + (long)n0 * Kdim + rowOff + kbase;
  u16* Aw = Albase + wave * 4096;   // [2 buf][2048 u16]
  u16* Bw = Blbase + wave * 4096;

  auto stageW = [&](int s, int p) {
    const int k0 = s * 32;
#pragma unroll
    for (int cc = 0; cc < 4; cc++) {   // 16 rows per gload, 64 rows per operand
      gload_lds16(gA + (long)(cc * 16) * Kdim + k0, Aw + p * 2048 + cc * 512);
      gload_lds16(gB + (long)(cc * 16) * Kdim + k0, Bw + p * 2048 + cc * 512);
    }
  };

  const int swz = (quad ^ ((l15 >> 1) & 3)) * 8;
  const int nSteps = Kdim >> 7;   // per-wave: (K/4)/32

  stageW(0, 0);
  stageW(1, 1);
  int p = 0;
  for (int s = 0; s < nSteps - 1; s++, p ^= 1) {
    // wait for step s's 8 gloads; leave step s+1's 8 in flight (never drain to 0)
    asm volatile("s_waitcnt vmcnt(8)" ::: "memory");
    bf16x8 af[4], bf[4];
#pragma unroll
    for (int mt = 0; mt < 4; mt++)
      af[mt] = *reinterpret_cast<const bf16x8*>(Aw + p * 2048 + (mt * 16 + l15) * 32 + swz);
#pragma unroll
    for (int nt = 0; nt < 4; nt++)
      bf[nt] = *reinterpret_cast<const bf16x8*>(Bw + p * 2048 + (nt * 16 + l15) * 32 + swz);
#pragma unroll
    for (int mt = 0; mt < 4; mt++)
#pragma unroll
      for (int nt = 0; nt < 4; nt++)
        acc[mt][nt] = __builtin_amdgcn_mfma_f32_16x16x32_bf16(af[mt], bf[nt], acc[mt][nt], 0, 0, 0);
    if (s < nSteps - 2) stageW(s + 2, p);   // after MFMAs: frag regs already consumed
  }
  asm volatile("s_waitcnt vmcnt(0)" ::: "memory");
  {
    bf16x8 af[4], bf[4];
#pragma unroll
    for (int mt = 0; mt < 4; mt++)
      af[mt] = *reinterpret_cast<const bf16x8*>(Aw + p * 2048 + (mt * 16 + l15) * 32 + swz);
#pragma unroll
    for (int nt = 0; nt < 4; nt++)
      bf[nt] = *reinterpret_cast<const bf16x8*>(Bw + p * 2048 + (nt * 16 + l15) * 32 + swz);
#pragma unroll
    for (int mt = 0; mt < 4; mt++)
#pragma unroll
      for (int nt = 0; nt < 4; nt++)
        acc[mt][nt] = __builtin_amdgcn_mfma_f32_16x16x32_bf16(af[mt], bf[nt], acc[mt][nt], 0, 0, 0);
  }

  // ---- cross-wave K reduction through LDS (staging area is dead now) ----
  __syncthreads();
  float* lf = reinterpret_cast<float*>(lds);   // 16384 f32 = 4 regions x 4096
  float* myreg = lf + wave * 4096;
#pragma unroll
  for (int mt = 0; mt < 4; mt++)
#pragma unroll
    for (int nt = 0; nt < 4; nt++)
      *reinterpret_cast<f32x4*>(myreg + lane * 64 + mt * 16 + nt * 4) = acc[mt][nt];
  __syncthreads();

  const int Lq  = lane >> 2;   // owner col sub-index
  const int mtR = lane & 3;    // owner mt
  f32x4 sum[4] = {vzero, vzero, vzero, vzero};
#pragma unroll
  for (int rg = 0; rg < 4; rg++) {
    const float* rp = lf + rg * 4096 + (wave * 16 + Lq) * 64 + mtR * 16;
#pragma unroll
    for (int nt = 0; nt < 4; nt++)
      sum[nt] += *reinterpret_cast<const f32x4*>(rp + nt * 4);
  }
#pragma unroll
  for (int nt = 0; nt < 4; nt++) {
    const int col = n0 + nt * 16 + Lq;
    const float bv = bias[col];
#pragma unroll
    for (int r = 0; r < 4; r++) {
      const int row = m0 + mtR * 16 + wave * 4 + r;
      Cout[(long)row * Ndim + col] = sum[nt][r] + bv + res[(long)row * Ndim + col];
    }
  }
}

// ------- Flash attention v8: KVBLK=128, XCD-clustered, cvt_pk, setprio ----------------
__global__ __launch_bounds__(256, 2) void attn_kernel(
    const u16* __restrict__ Q, const u16* __restrict__ K, const u16* __restrict__ Vt,
    u16* __restrict__ O, int nk, int qStride, int kStride, int oStride,
    long qBatch, long kBatch, long oBatch) {
  __shared__ u16 Kt[2][2 * 64 * 64];
  __shared__ u16 Vl[2][2 * 64 * 64];
  __shared__ u16 Pl[4][32 * 64];

  const int tid = threadIdx.x;
  const int lane = tid & 63, wave = tid >> 6;
  const int quad = lane >> 4, l15 = lane & 15;

  const int j = blockIdx.x;
  const int xcd = j & 7, slot = j >> 3;
  const int g = xcd * 4 + (slot >> 4);
  const int qt = slot & 15;
  const int hh = g & 15, b = g >> 4;

  const u16* qp = Q + (long)b * qBatch + hh * 64;
  const u16* kp = K + (long)b * kBatch + hh * 64;
  const u16* vp = Vt + (long)(b * 16 + hh) * 64 * (long)nk;

  bf16x8 qf[2][2];
  const int qrow = qt * 128 + wave * 32 + l15;
#pragma unroll
  for (int qg = 0; qg < 2; qg++) {
    qf[qg][0] = *reinterpret_cast<const bf16x8*>(qp + (long)(qrow + qg * 16) * qStride + quad * 8);
    qf[qg][1] = *reinterpret_cast<const bf16x8*>(qp + (long)(qrow + qg * 16) * qStride + 32 + quad * 8);
  }

  const int r8 = lane >> 3;
  const int gcol = ((lane & 7) ^ r8) * 8;
  const u16* kgA = kp + (long)(wave * 8 + r8) * kStride + gcol;
  const u16* kgB = kp + (long)((wave + 4) * 8 + r8) * kStride + gcol;
  const u16* vgA = vp + (long)(wave * 8 + r8) * nk + gcol;
  const u16* vgB = vp + (long)((wave + 4) * 8 + r8) * nk + gcol;

  const int cF = (quad ^ (l15 & 7)) * 8;

  const f32x4 vzero = {0.f, 0.f, 0.f, 0.f};
  const bf16x8 vones = {16256, 16256, 16256, 16256, 16256, 16256, 16256, 16256};
  f32x4 oAcc[2][4];
  f32x4 lAcc[2];
#pragma unroll
  for (int qg = 0; qg < 2; qg++) {
    lAcc[qg] = vzero;
#pragma unroll
    for (int i = 0; i < 4; i++) oAcc[qg][i] = vzero;
  }

  const int nWin = nk >> 7;
  const long kAdv = (long)128 * kStride;

  auto stage = [&](int w, int p) {
#pragma unroll
    for (int h2 = 0; h2 < 2; h2++) {
      const long kOff = w * kAdv + (long)(h2 * 64) * kStride;
      gload_lds16(kgA + kOff, &Kt[p][h2 * 4096 + wave * 512]);
      gload_lds16(kgB + kOff, &Kt[p][h2 * 4096 + (wave + 4) * 512]);
      const int vOff = w * 128 + h2 * 64;
      gload_lds16(vgA + vOff, &Vl[p][h2 * 4096 + wave * 512]);
      gload_lds16(vgB + vOff, &Vl[p][h2 * 4096 + (wave + 4) * 512]);
    }
  };

  stage(0, 0);
  int p = 0;
  for (int w = 0; w < nWin; w++, p ^= 1) {
    __syncthreads();
    if (w + 1 < nWin) stage(w + 1, p ^ 1);

#pragma unroll
    for (int h2 = 0; h2 < 2; h2++) {
      const u16* Kh = &Kt[p][h2 * 4096];
      const u16* Vh = &Vl[p][h2 * 4096];

      f32x4 st[2][4];
      __builtin_amdgcn_s_setprio(1);
#pragma unroll
      for (int mt = 0; mt < 4; mt++) {
        const bf16x8 kf0 = *reinterpret_cast<const bf16x8*>(&Kh[(mt * 16 + l15) * 64 + cF]);
        const bf16x8 kf1 = *reinterpret_cast<const bf16x8*>(&Kh[(mt * 16 + l15) * 64 + (cF ^ 32)]);
#pragma unroll
        for (int qg = 0; qg < 2; qg++) {
          f32x4 z = vzero;
          z = __builtin_amdgcn_mfma_f32_16x16x32_bf16(kf0, qf[qg][0], z, 0, 0, 0);
          z = __builtin_amdgcn_mfma_f32_16x16x32_bf16(kf1, qf[qg][1], z, 0, 0, 0);
          st[qg][mt] = z;
        }
      }
      __builtin_amdgcn_s_setprio(0);

#pragma unroll
      for (int qg = 0; qg < 2; qg++) {
        u16* plw = &Pl[wave][(qg * 16 + l15) * 64];
#pragma unroll
        for (int mt = 0; mt < 4; mt++) {
          const float e0 = __builtin_amdgcn_exp2f(st[qg][mt][0]);
          const float e1 = __builtin_amdgcn_exp2f(st[qg][mt][1]);
          const float e2 = __builtin_amdgcn_exp2f(st[qg][mt][2]);
          const float e3 = __builtin_amdgcn_exp2f(st[qg][mt][3]);
          uint2 w2;
          asm("v_cvt_pk_bf16_f32 %0, %1, %2" : "=v"(w2.x) : "v"(e0), "v"(e1));
          asm("v_cvt_pk_bf16_f32 %0, %1, %2" : "=v"(w2.y) : "v"(e2), "v"(e3));
          const int pcol = (((mt * 2 + (quad >> 1)) ^ (l15 & 7)) * 8) + (quad & 1) * 4;
          *reinterpret_cast<uint2*>(&plw[pcol]) = w2;
        }
      }

      bf16x8 pf[2][2];
#pragma unroll
      for (int qg = 0; qg < 2; qg++) {
        const u16* plw = &Pl[wave][(qg * 16 + l15) * 64];
        pf[qg][0] = *reinterpret_cast<const bf16x8*>(&plw[cF]);
        pf[qg][1] = *reinterpret_cast<const bf16x8*>(&plw[cF ^ 32]);
        lAcc[qg] = __builtin_amdgcn_mfma_f32_16x16x32_bf16(pf[qg][0], vones, lAcc[qg], 0, 0, 0);
        lAcc[qg] = __builtin_amdgcn_mfma_f32_16x16x32_bf16(pf[qg][1], vones, lAcc[qg], 0, 0, 0);
      }
      __builtin_amdgcn_s_setprio(1);
#pragma unroll
      for (int dt = 0; dt < 4; dt++) {
        const bf16x8 vf0 = *reinterpret_cast<const bf16x8*>(&Vh[(dt * 16 + l15) * 64 + cF]);
        const bf16x8 vf1 = *reinterpret_cast<const bf16x8*>(&Vh[(dt * 16 + l15) * 64 + (cF ^ 32)]);
#pragma unroll
        for (int qg = 0; qg < 2; qg++) {
          oAcc[qg][dt] = __builtin_amdgcn_mfma_f32_16x16x32_bf16(pf[qg][0], vf0, oAcc[qg][dt], 0, 0, 0);
          oAcc[qg][dt] = __builtin_amdgcn_mfma_f32_16x16x32_bf16(pf[qg][1], vf1, oAcc[qg][dt], 0, 0, 0);
        }
      }
      __builtin_amdgcn_s_setprio(0);
    }
  }

  u16* op = O + (long)b * oBatch + hh * 64;
#pragma unroll
  for (int qg = 0; qg < 2; qg++) {
    float lR[4];
#pragma unroll
    for (int r = 0; r < 4; r++) lR[r] = 1.0f / lAcc[qg][r];
#pragma unroll
    for (int dt = 0; dt < 4; dt++)
#pragma unroll
      for (int r = 0; r < 4; r++) {
        const int row = qt * 128 + wave * 32 + qg * 16 + quad * 4 + r;
        op[(long)row * oStride + dt * 16 + l15] = f2bf(oAcc[qg][dt][r] * lR[r]);
      }
  }
}

// ---------------- launcher ----------------
extern "C" void kernel_launch(void* const* d_in, const int* in_sizes, int n_in,
                              void* d_out, int out_size, void* d_ws, size_t ws_size,
                              hipStream_t stream) {
  const float* x    = (const float*)d_in[0];
  const float* ctx  = (const float*)d_in[1];
  const float* Wqkv = (const float*)d_in[2];
  const float* bqkv = (const float*)d_in[3];
  const float* Wos  = (const float*)d_in[4];
  const float* bos  = (const float*)d_in[5];
  const float* Wq   = (const float*)d_in[6];
  const float* bq   = (const float*)d_in[7];
  const float* Wkv  = (const float*)d_in[8];
  const float* bkv  = (const float*)d_in[9];
  const float* Woc  = (const float*)d_in[10];
  const float* boc  = (const float*)d_in[11];
  const float* W1   = (const float*)d_in[12];
  const float* b1   = (const float*)d_in[13];
  const float* W2   = (const float*)d_in[14];
  const float* b2   = (const float*)d_in[15];
  float* out = (float*)d_out;
  char* ws = (char*)d_ws;
  const size_t MB = 1024 * 1024;
  const float SCL = 0.18033688f;   // log2(e) / sqrt(64)

  u16* h      = (u16*)ws;
  u16* abuf   = (u16*)(ws + 8 * MB);
  u16* wbuf   = (u16*)(ws + 8 * MB);
  u16* qkv    = (u16*)(ws + 16 * MB);
  u16* Wqkvt  = (u16*)(ws + 40 * MB);
  u16* Wost   = (u16*)(ws + 16 * MB);
  u16* Wqt    = (u16*)(ws + 18 * MB);
  u16* Wkvt   = (u16*)(ws + 20 * MB);
  u16* Woct   = (u16*)(ws + 24 * MB);
  u16* q2     = (u16*)(ws + 26 * MB);
  u16* kv2    = (u16*)(ws + 34 * MB);
  u16* ctxbf  = (u16*)(ws + 42 * MB);
  u16* VtCr   = (u16*)(ws + 16 * MB);
  u16* hid    = (u16*)(ws + 16 * MB);
  u16* VtSelf = h;
  u16* W1t    = wbuf;
  const bool bigWs = (ws_size >= 56 * MB);
  u16* W2t    = bigWs ? (u16*)(ws + 48 * MB) : wbuf;

  WEnts w1; w1.n = 1;

  // ---- self-attention branch ----
  w1.e[0] = {Wqkv, Wqkvt, 1024, 3072, 768};
  ln_wconv_combo<<<dim3(4096 + 768), dim3(256), 0, stream>>>(x, h, 4096, w1);
  gemm_bt<64, 2, true, false, false><<<dim3(1536), dim3(256), 0, stream>>>(
      h, Wqkvt, bqkv, nullptr, qkv, 3072, 1024, 24, 8, 1024, SCL);
  vtrans<<<dim3(32, 16, 2), dim3(256), 0, stream>>>(
      qkv + 2048, VtSelf, 3072, (long)2048 * 3072, 2048);
  attn_kernel<<<dim3(512), dim3(256), 0, stream>>>(
      qkv, qkv + 1024, VtSelf, abuf, 2048, 3072, 3072, 1024,
      (long)2048 * 3072, (long)2048 * 3072, (long)2048 * 1024);

  // ---- batched wconvert for next 4 GEMMs + f2bf(ctx) ----
  WEnts w4; w4.n = 4;
  w4.e[0] = {Wos, Wost, 1024, 1024, 256};
  w4.e[1] = {Wq,  Wqt,  1024, 1024, 512};
  w4.e[2] = {Wkv, Wkvt, 1024, 2048, 1024};
  w4.e[3] = {Woc, Woct, 1024, 1024, 1280};
  wconv_f2bf_combo<<<dim3(1280 + 2048), dim3(256), 0, stream>>>(w4, 1280, ctx, ctxbf);

  gemm_bt<64, 1, false, false, true><<<dim3(512), dim3(256), 0, stream>>>(
      abuf, Wost, bos, x, out, 1024, 1024, 16, 4, 0, 1.0f);
  ln_kernel<<<dim3(4096), dim3(256), 0, stream>>>(out, h);

  // ---- cross-attention branch ----
  GemmDualP dp;
  dp.s0 = {h,     Wqt,  bq,  q2,  1024, 1024, 1, 16, 4, 1024, SCL};
  dp.s1 = {ctxbf, Wkvt, bkv, kv2, 2048, 1024, 2, 16, 4, 0, 1.0f};
  dp.nBlk0 = 512;
  gemm_dual<64><<<dim3(1024), dim3(256), 0, stream>>>(dp);
  vtrans<<<dim3(16, 16, 2), dim3(256), 0, stream>>>(
      kv2 + 1024, VtCr, 2048, (long)1024 * 2048, 1024);
  attn_kernel<<<dim3(512), dim3(256), 0, stream>>>(
      q2, kv2, VtCr, abuf, 1024, 1024, 2048, 1024,
      (long)2048 * 1024, (long)1024 * 2048, (long)2048 * 1024);
  gemm_bt<64, 1, false, false, true><<<dim3(512), dim3(256), 0, stream>>>(
      abuf, Woct, boc, out, out, 1024, 1024, 16, 4, 0, 1.0f);

  // ---- MLP ----
  if (bigWs) {
    WEnts w2c; w2c.n = 2;
    w2c.e[0] = {W1, W1t, 1024, 4096, 1024};
    w2c.e[1] = {W2, W2t, 4096, 1024, 2048};
    ln_wconv_combo<<<dim3(4096 + 2048), dim3(256), 0, stream>>>(out, h, 4096, w2c);
    gemm_bt<128, 2, true, true, false><<<dim3(1024), dim3(256), 0, stream>>>(
        h, W1t, b1, nullptr, hid, 4096, 1024, 16, 8, 0, 1.0f);
  } else {
    w1.e[0] = {W1, W1t, 1024, 4096, 1024};
    ln_wconv_combo<<<dim3(4096 + 1024), dim3(256), 0, stream>>>(out, h, 4096, w1);
    gemm_bt<128, 2, true, true, false><<<dim3(1024), dim3(256), 0, stream>>>(
        h, W1t, b1, nullptr, hid, 4096, 1024, 16, 8, 0, 1.0f);
    w1.e[0] = {W2, W2t, 4096, 1024, 1024};
    wconvert_all<<<dim3(1024), dim3(256), 0, stream>>>(w1);
  }
  // W2: wave-split-K barrier-free kernel, 64x64 tiles -> 1024 blocks (2 blk/CU)
  gemm_wsk<<<dim3(1024), dim3(256), 0, stream>>>(
      hid, W2t, b2, out, out, 1024, 4096);
}

// Round 16
// 416.045 us; speedup vs baseline: 1.0813x; 1.0813x over previous
//
#include <hip/hip_runtime.h>
#include <cstdint>

typedef unsigned short u16;
typedef short bf16x8 __attribute__((ext_vector_type(8)));
typedef unsigned short u16x8 __attribute__((ext_vector_type(8)));
typedef float f32x4 __attribute__((ext_vector_type(4)));

__device__ __forceinline__ u16 f2bf(float f) {
  union { float f; uint32_t u; } v; v.f = f;
  uint32_t r = (v.u + 0x7fffu + ((v.u >> 16) & 1u)) >> 16;
  return (u16)r;
}

__device__ __forceinline__ void gload_lds16(const u16* g, u16* l) {
  __builtin_amdgcn_global_load_lds(
      (const __attribute__((address_space(1))) void*)g,
      (__attribute__((address_space(3))) void*)l, 16, 0, 0);
}

// ---------------- LayerNorm body: fp32 in -> bf16 out, C = 1024 ----------------
__device__ __forceinline__ void ln_body(const float* __restrict__ x,
                                        u16* __restrict__ h, int row) {
  const int tid = threadIdx.x;
  const float4 v = *reinterpret_cast<const float4*>(x + (long)row * 1024 + tid * 4);
  float s  = v.x + v.y + v.z + v.w;
  float ss = v.x * v.x + v.y * v.y + v.z * v.z + v.w * v.w;
#pragma unroll
  for (int off = 32; off >= 1; off >>= 1) {
    s  += __shfl_xor(s, off, 64);
    ss += __shfl_xor(ss, off, 64);
  }
  __shared__ float red[8];
  const int wave = tid >> 6, lane = tid & 63;
  if (lane == 0) { red[wave] = s; red[4 + wave] = ss; }
  __syncthreads();
  s  = red[0] + red[1] + red[2] + red[3];
  ss = red[4] + red[5] + red[6] + red[7];
  const float mu   = s * (1.0f / 1024.0f);
  const float var  = ss * (1.0f / 1024.0f) - mu * mu;
  const float rstd = rsqrtf(var + 1e-6f);
  ushort4 o;
  o.x = f2bf((v.x - mu) * rstd);
  o.y = f2bf((v.y - mu) * rstd);
  o.z = f2bf((v.z - mu) * rstd);
  o.w = f2bf((v.w - mu) * rstd);
  *reinterpret_cast<ushort4*>(h + (long)row * 1024 + tid * 4) = o;
}

__global__ __launch_bounds__(256) void ln_kernel(const float* __restrict__ x,
                                                 u16* __restrict__ h) {
  ln_body(x, h, blockIdx.x);
}

// ------------- weight transpose+convert body: W[K][N] fp32 -> Wt[N][K] bf16 ----------
struct WEnt { const float* W; u16* Wt; int K, N, tEnd; };
struct WEnts { WEnt e[4]; int n; };

__device__ __forceinline__ void wconv_body(const WEnts& args, int t) {
  __shared__ u16 tile[64][72];
  int i = 0, tStart = 0;
  while (i < args.n - 1 && t >= args.e[i].tEnd) { tStart = args.e[i].tEnd; i++; }
  const float* W = args.e[i].W;
  u16* Wt = args.e[i].Wt;
  const int K = args.e[i].K, N = args.e[i].N;
  const int rel = t - tStart;
  const int ntn = N >> 6;
  const int tn = rel % ntn, tk = rel / ntn;
  const int n0 = tn * 64, k0 = tk * 64;

  const int th = threadIdx.x;
  const int c4 = (th & 15) * 4;
  const int r  = th >> 4;
#pragma unroll
  for (int ii = 0; ii < 4; ii++) {
    const int row = ii * 16 + r;
    const float4 v = *reinterpret_cast<const float4*>(W + (long)(k0 + row) * N + n0 + c4);
    tile[c4 + 0][row] = f2bf(v.x);
    tile[c4 + 1][row] = f2bf(v.y);
    tile[c4 + 2][row] = f2bf(v.z);
    tile[c4 + 3][row] = f2bf(v.w);
  }
  __syncthreads();
  const int c8 = (th & 7) * 8;
  const int rn = th >> 3;
#pragma unroll
  for (int ii = 0; ii < 2; ii++) {
    const int row = ii * 32 + rn;
    *reinterpret_cast<u16x8*>(Wt + (long)(n0 + row) * K + k0 + c8) =
        *reinterpret_cast<const u16x8*>(&tile[row][c8]);
  }
}

__global__ __launch_bounds__(256) void wconvert_all(WEnts args) {
  wconv_body(args, blockIdx.x);
}

// ---- combo: ln rows [0,nLn) + weight-convert tiles [nLn, nLn+tiles) in one grid ----
__global__ __launch_bounds__(256) void ln_wconv_combo(const float* __restrict__ x,
                                                      u16* __restrict__ h, int nLn,
                                                      WEnts args) {
  if ((int)blockIdx.x < nLn) ln_body(x, h, blockIdx.x);
  else                       wconv_body(args, blockIdx.x - nLn);
}

// ---- combo: weight-convert tiles [0,nW) + fp32->bf16 blocks [nW, ...) -------------
__global__ __launch_bounds__(256) void wconv_f2bf_combo(WEnts args, int nW,
                                                        const float* __restrict__ in,
                                                        u16* __restrict__ out) {
  if ((int)blockIdx.x < nW) {
    wconv_body(args, blockIdx.x);
  } else {
    const long i = ((long)(blockIdx.x - nW) * 256 + threadIdx.x) * 4;
    const float4 v = *reinterpret_cast<const float4*>(in + i);
    ushort4 o;
    o.x = f2bf(v.x); o.y = f2bf(v.y); o.z = f2bf(v.z); o.w = f2bf(v.w);
    *reinterpret_cast<ushort4*>(out + i) = o;
  }
}

// ------- V transpose (coalesced LDS-tile): V[b][n][..h*64+d] -> Vt[(b*16+h)][d][nk] ----
__global__ __launch_bounds__(256) void vtrans(const u16* __restrict__ V,
                                              u16* __restrict__ Vt,
                                              int vStride, long vBatch, int nk) {
  __shared__ u16 tile[64][72];
  const int t = threadIdx.x;
  const int b = blockIdx.z, h = blockIdx.y, n0 = blockIdx.x * 64;
  const u16* vp = V + (long)b * vBatch + h * 64;
  u16* op = Vt + (long)(b * 16 + h) * 64 * (long)nk + n0;
  const int ch = t & 7;
#pragma unroll
  for (int i = 0; i < 2; i++) {
    const int n = (t >> 3) + i * 32;
    const u16x8 v = *reinterpret_cast<const u16x8*>(vp + (long)(n0 + n) * vStride + ch * 8);
#pragma unroll
    for (int j = 0; j < 8; j++) tile[ch * 8 + j][n] = v[j];
  }
  __syncthreads();
#pragma unroll
  for (int i = 0; i < 2; i++) {
    const int d = (t >> 3) + i * 32;
    *reinterpret_cast<u16x8*>(op + (long)d * nk + ch * 8) =
        *reinterpret_cast<const u16x8*>(&tile[d][ch * 8]);
  }
}

// ------- GEMM core BK=64: 2-buffer dbuf prefetch; TN in {64,128} ----------------------
// C = act(A @ Bt^T + bias) (+res).  TM=128 fixed (2x2 wave grid, wave = 64 x TN/2).
// Window order (R10/R12-proven): frag ds_reads FIRST, then stage(t+1) issue, then MFMA.
// Stage-first regressed 27% (R11); wave-private barrier-free pipelines regressed 81%
// (R15: lost cross-wave issue overlap + doubled panel re-reads) — this structure is
// the measured argmax of the family.
// qcols/qscale: columns < qcols multiplied by qscale post-bias (pre-scaled Q).
// LDS tile: [row][64 u16]; granule g of row r at physical granule g ^ (r&7); staged
// via pre-permuted per-lane GLOBAL source granule (gload_lds dest stays LINEAR);
// fragment reads apply the same XOR.
template <int TN, bool OUT_BF16, bool GELU_ACT, bool RES>
__device__ __forceinline__ void gemm_core(
    const u16* __restrict__ A, const u16* __restrict__ Bt,
    const float* __restrict__ bias, const float* __restrict__ res,
    void* __restrict__ Cout, int Ndim, int Kdim, int m0, int n0,
    u16* Al, u16* Bl, int qcols, float qscale) {
  constexpr int NF = TN / 32;
  constexpr int ABUF = 128 * 64;   // u16 per A buffer
  constexpr int BBUF = TN * 64;
  const int tid  = threadIdx.x;
  const int lane = tid & 63, wave = tid >> 6;
  const int quad = lane >> 4, l15 = lane & 15;
  const int wr = wave >> 1, wc = wave & 1;

  f32x4 acc[4][NF];
  const f32x4 vzero = {0.f, 0.f, 0.f, 0.f};
#pragma unroll
  for (int i = 0; i < 4; i++)
#pragma unroll
    for (int jj = 0; jj < NF; jj++) acc[i][jj] = vzero;

  // per-lane staging source: row (lane>>3) within each 8-row chunk, permuted granule
  const int srcRow = lane >> 3;
  const int srcG   = ((lane & 7) ^ (srcRow & 7)) * 8;
  const u16* gA = A  + (long)(m0 + srcRow) * Kdim + srcG;
  const u16* gB = Bt + (long)(n0 + srcRow) * Kdim + srcG;

  auto stage = [&](int k0, int p) {
#pragma unroll
    for (int i = 0; i < 4; i++)   // A: 128 rows = 4 waves x 4 chunks x 8 rows
      gload_lds16(gA + (long)(wave * 32 + i * 8) * Kdim + k0,
                  Al + p * ABUF + wave * 2048 + i * 512);
#pragma unroll
    for (int i = 0; i < TN / 32; i++)  // B: TN rows = 4 waves x (TN/32) chunks x 8 rows
      gload_lds16(gB + (long)(wave * (TN / 4) + i * 8) * Kdim + k0,
                  Bl + p * BBUF + wave * (TN * 16) + i * 512);
  };

  // fragment-read swizzle (row&7 == l15&7 since row-base is a multiple of 8)
  const int off0 = (quad ^ (l15 & 7)) * 8;

  stage(0, 0);
  int p = 0;
  for (int k0 = 0; k0 < Kdim; k0 += 64, p ^= 1) {
    __syncthreads();  // drains prev prefetch (vmcnt) + prev frag reads (lgkm)
    bf16x8 af[2][4], bfr[2][NF];
    const u16* ab = Al + p * ABUF;
    const u16* bb = Bl + p * BBUF;
#pragma unroll
    for (int mt = 0; mt < 4; mt++) {
      const int r = (wr * 64 + mt * 16 + l15) * 64;
      af[0][mt] = *reinterpret_cast<const bf16x8*>(ab + r + off0);
      af[1][mt] = *reinterpret_cast<const bf16x8*>(ab + r + (off0 ^ 32));
    }
#pragma unroll
    for (int nt = 0; nt < NF; nt++) {
      const int r = (wc * (NF * 16) + nt * 16 + l15) * 64;
      bfr[0][nt] = *reinterpret_cast<const bf16x8*>(bb + r + off0);
      bfr[1][nt] = *reinterpret_cast<const bf16x8*>(bb + r + (off0 ^ 32));
    }
    if (k0 + 64 < Kdim) stage(k0 + 64, p ^ 1);  // prefetch overlaps MFMA below
#pragma unroll
    for (int s = 0; s < 2; s++)
#pragma unroll
      for (int mt = 0; mt < 4; mt++)
#pragma unroll
        for (int nt = 0; nt < NF; nt++)
          acc[mt][nt] = __builtin_amdgcn_mfma_f32_16x16x32_bf16(af[s][mt], bfr[s][nt], acc[mt][nt], 0, 0, 0);
  }

#pragma unroll
  for (int nt = 0; nt < NF; nt++) {
    const int col = n0 + wc * (NF * 16) + nt * 16 + l15;
    const float bv = bias[col];
    const float cs = (col < qcols) ? qscale : 1.0f;
#pragma unroll
    for (int mt = 0; mt < 4; mt++) {
#pragma unroll
      for (int r = 0; r < 4; r++) {
        const int row = m0 + wr * 64 + mt * 16 + quad * 4 + r;
        float y = (acc[mt][nt][r] + bv) * cs;
        if (GELU_ACT) {
          // 0.5*y*(1+tanh(t)) == y * sigmoid(2t) == y / (1 + exp2(-2t/ln2))
          const float t = 0.7978845608028654f * (y + 0.044715f * y * y * y);
          y = y / (1.0f + __builtin_amdgcn_exp2f(-2.885390081777927f * t));
        }
        if (RES) y += res[(long)row * Ndim + col];
        if (OUT_BF16)
          ((u16*)Cout)[(long)row * Ndim + col] = f2bf(y);
        else
          ((float*)Cout)[(long)row * Ndim + col] = y;
      }
    }
  }
}

// standalone GEMM kernel (XCD-swizzled block decode); TM=128 fixed
template <int TN, int SX, bool OUT_BF16, bool GELU_ACT, bool RES>
__global__ __launch_bounds__(256, 2) void gemm_bt(
    const u16* __restrict__ A, const u16* __restrict__ Bt,
    const float* __restrict__ bias, const float* __restrict__ res,
    void* __restrict__ Cout, int Ndim, int Kdim, int lx, int ly,
    int qcols, float qscale) {
  __shared__ u16 Al[2 * 128 * 64];
  __shared__ u16 Bl[2 * TN * 64];
  const int j = blockIdx.x;
  const int c = j & 7, kk = j >> 3;
  const int cx = c % SX, cy = c / SX;
  const int bx = cx * lx + (kk % lx);
  const int by = cy * ly + (kk / lx);
  gemm_core<TN, OUT_BF16, GELU_ACT, RES>(
      A, Bt, bias, res, Cout, Ndim, Kdim, by * 128, bx * TN, Al, Bl, qcols, qscale);
}

// dual-segment GEMM: two independent bf16-out GEMMs in one grid (one dispatch).
struct GemmSeg {
  const u16* A; const u16* Bt; const float* bias; u16* C;
  int Ndim, Kdim, SX, lx, ly, qcols; float qscale;
};
struct GemmDualP { GemmSeg s0, s1; int nBlk0; };

template <int TN>
__global__ __launch_bounds__(256, 2) void gemm_dual(GemmDualP pp) {
  __shared__ u16 Al[2 * 128 * 64];
  __shared__ u16 Bl[2 * TN * 64];
  int j = blockIdx.x;
  GemmSeg s;
  if (j < pp.nBlk0) { s = pp.s0; } else { s = pp.s1; j -= pp.nBlk0; }
  const int c = j & 7, kk = j >> 3;  // nBlk0 % 8 == 0 keeps XCD bits aligned
  const int cx = c % s.SX, cy = c / s.SX;
  const int bx = cx * s.lx + (kk % s.lx);
  const int by = cy * s.ly + (kk / s.lx);
  gemm_core<TN, true, false, false>(
      s.A, s.Bt, s.bias, nullptr, s.C, s.Ndim, s.Kdim, by * 128, bx * TN, Al, Bl,
      s.qcols, s.qscale);
}

// ------- Flash attention v8: KVBLK=128, XCD-clustered, cvt_pk, setprio ----------------
// 1-D grid of 512 blocks; decode clusters all 16 qt-blocks of one (b,hh) K/V panel on
// a single XCD so the panel is fetched into that XCD's L2 once.
__global__ __launch_bounds__(256, 2) void attn_kernel(
    const u16* __restrict__ Q, const u16* __restrict__ K, const u16* __restrict__ Vt,
    u16* __restrict__ O, int nk, int qStride, int kStride, int oStride,
    long qBatch, long kBatch, long oBatch) {
  __shared__ u16 Kt[2][2 * 64 * 64];   // 32 KB: two [64][64] halves per buffer
  __shared__ u16 Vl[2][2 * 64 * 64];   // 32 KB
  __shared__ u16 Pl[4][32 * 64];       // 16 KB

  const int tid = threadIdx.x;
  const int lane = tid & 63, wave = tid >> 6;
  const int quad = lane >> 4, l15 = lane & 15;

  // XCD-clustered decode: j -> (qt, hh, b); 8 xcd x 4 groups x 16 qt = 512
  const int j = blockIdx.x;
  const int xcd = j & 7, slot = j >> 3;
  const int g = xcd * 4 + (slot >> 4);
  const int qt = slot & 15;
  const int hh = g & 15, b = g >> 4;

  const u16* qp = Q + (long)b * qBatch + hh * 64;
  const u16* kp = K + (long)b * kBatch + hh * 64;
  const u16* vp = Vt + (long)(b * 16 + hh) * 64 * (long)nk;

  bf16x8 qf[2][2];
  const int qrow = qt * 128 + wave * 32 + l15;
#pragma unroll
  for (int qg = 0; qg < 2; qg++) {
    qf[qg][0] = *reinterpret_cast<const bf16x8*>(qp + (long)(qrow + qg * 16) * qStride + quad * 8);
    qf[qg][1] = *reinterpret_cast<const bf16x8*>(qp + (long)(qrow + qg * 16) * qStride + 32 + quad * 8);
  }

  const int r8 = lane >> 3;
  const int gcol = ((lane & 7) ^ r8) * 8;
  const u16* kgA = kp + (long)(wave * 8 + r8) * kStride + gcol;
  const u16* kgB = kp + (long)((wave + 4) * 8 + r8) * kStride + gcol;
  const u16* vgA = vp + (long)(wave * 8 + r8) * nk + gcol;
  const u16* vgB = vp + (long)((wave + 4) * 8 + r8) * nk + gcol;

  const int cF = (quad ^ (l15 & 7)) * 8;

  const f32x4 vzero = {0.f, 0.f, 0.f, 0.f};
  const bf16x8 vones = {16256, 16256, 16256, 16256, 16256, 16256, 16256, 16256}; // bf16 1.0
  f32x4 oAcc[2][4];
  f32x4 lAcc[2];
#pragma unroll
  for (int qg = 0; qg < 2; qg++) {
    lAcc[qg] = vzero;
#pragma unroll
    for (int i = 0; i < 4; i++) oAcc[qg][i] = vzero;
  }

  const int nWin = nk >> 7;             // 128 KV rows per window
  const long kAdv = (long)128 * kStride;

  auto stage = [&](int w, int p) {
#pragma unroll
    for (int h2 = 0; h2 < 2; h2++) {
      const long kOff = w * kAdv + (long)(h2 * 64) * kStride;
      gload_lds16(kgA + kOff, &Kt[p][h2 * 4096 + wave * 512]);
      gload_lds16(kgB + kOff, &Kt[p][h2 * 4096 + (wave + 4) * 512]);
      const int vOff = w * 128 + h2 * 64;
      gload_lds16(vgA + vOff, &Vl[p][h2 * 4096 + wave * 512]);
      gload_lds16(vgB + vOff, &Vl[p][h2 * 4096 + (wave + 4) * 512]);
    }
  };

  stage(0, 0);
  int p = 0;
  for (int w = 0; w < nWin; w++, p ^= 1) {
    __syncthreads();
    if (w + 1 < nWin) stage(w + 1, p ^ 1);

#pragma unroll
    for (int h2 = 0; h2 < 2; h2++) {
      const u16* Kh = &Kt[p][h2 * 4096];
      const u16* Vh = &Vl[p][h2 * 4096];

      f32x4 st[2][4];
      __builtin_amdgcn_s_setprio(1);
#pragma unroll
      for (int mt = 0; mt < 4; mt++) {
        const bf16x8 kf0 = *reinterpret_cast<const bf16x8*>(&Kh[(mt * 16 + l15) * 64 + cF]);
        const bf16x8 kf1 = *reinterpret_cast<const bf16x8*>(&Kh[(mt * 16 + l15) * 64 + (cF ^ 32)]);
#pragma unroll
        for (int qg = 0; qg < 2; qg++) {
          f32x4 z = vzero;
          z = __builtin_amdgcn_mfma_f32_16x16x32_bf16(kf0, qf[qg][0], z, 0, 0, 0);
          z = __builtin_amdgcn_mfma_f32_16x16x32_bf16(kf1, qf[qg][1], z, 0, 0, 0);
          st[qg][mt] = z;
        }
      }
      __builtin_amdgcn_s_setprio(0);

#pragma unroll
      for (int qg = 0; qg < 2; qg++) {
        u16* plw = &Pl[wave][(qg * 16 + l15) * 64];
#pragma unroll
        for (int mt = 0; mt < 4; mt++) {
          const float e0 = __builtin_amdgcn_exp2f(st[qg][mt][0]);
          const float e1 = __builtin_amdgcn_exp2f(st[qg][mt][1]);
          const float e2 = __builtin_amdgcn_exp2f(st[qg][mt][2]);
          const float e3 = __builtin_amdgcn_exp2f(st[qg][mt][3]);
          uint2 w2;
          asm("v_cvt_pk_bf16_f32 %0, %1, %2" : "=v"(w2.x) : "v"(e0), "v"(e1));
          asm("v_cvt_pk_bf16_f32 %0, %1, %2" : "=v"(w2.y) : "v"(e2), "v"(e3));
          const int pcol = (((mt * 2 + (quad >> 1)) ^ (l15 & 7)) * 8) + (quad & 1) * 4;
          *reinterpret_cast<uint2*>(&plw[pcol]) = w2;
        }
      }

      bf16x8 pf[2][2];
#pragma unroll
      for (int qg = 0; qg < 2; qg++) {
        const u16* plw = &Pl[wave][(qg * 16 + l15) * 64];
        pf[qg][0] = *reinterpret_cast<const bf16x8*>(&plw[cF]);
        pf[qg][1] = *reinterpret_cast<const bf16x8*>(&plw[cF ^ 32]);
        // denominator: l[q] = P @ 1 (every output column holds the row sum)
        lAcc[qg] = __builtin_amdgcn_mfma_f32_16x16x32_bf16(pf[qg][0], vones, lAcc[qg], 0, 0, 0);
        lAcc[qg] = __builtin_amdgcn_mfma_f32_16x16x32_bf16(pf[qg][1], vones, lAcc[qg], 0, 0, 0);
      }
      __builtin_amdgcn_s_setprio(1);
#pragma unroll
      for (int dt = 0; dt < 4; dt++) {
        const bf16x8 vf0 = *reinterpret_cast<const bf16x8*>(&Vh[(dt * 16 + l15) * 64 + cF]);
        const bf16x8 vf1 = *reinterpret_cast<const bf16x8*>(&Vh[(dt * 16 + l15) * 64 + (cF ^ 32)]);
#pragma unroll
        for (int qg = 0; qg < 2; qg++) {
          oAcc[qg][dt] = __builtin_amdgcn_mfma_f32_16x16x32_bf16(pf[qg][0], vf0, oAcc[qg][dt], 0, 0, 0);
          oAcc[qg][dt] = __builtin_amdgcn_mfma_f32_16x16x32_bf16(pf[qg][1], vf1, oAcc[qg][dt], 0, 0, 0);
        }
      }
      __builtin_amdgcn_s_setprio(0);
    }
  }

  u16* op = O + (long)b * oBatch + hh * 64;
#pragma unroll
  for (int qg = 0; qg < 2; qg++) {
    float lR[4];
#pragma unroll
    for (int r = 0; r < 4; r++) lR[r] = 1.0f / lAcc[qg][r];
#pragma unroll
    for (int dt = 0; dt < 4; dt++)
#pragma unroll
      for (int r = 0; r < 4; r++) {
        const int row = qt * 128 + wave * 32 + qg * 16 + quad * 4 + r;
        op[(long)row * oStride + dt * 16 + l15] = f2bf(oAcc[qg][dt][r] * lR[r]);
      }
  }
}

// ---------------- launcher ----------------
// Workspace layout (requires ws >= 48 MB; lifetime-audited):
//   h      [ 0, 8)   ln output; later reused as VtSelf
//   abuf   [ 8,16)   attn output; also W1t / W2t slot late
//   qkv    [16,40)   dead after attn-self
//   Wqkvt  [40,46)   dead after qkv GEMM
//   -- after attn-self (qkv,Wqkvt dead): --
//   Wost   [16,18)  Wqt [18,20)  Wkvt [20,24)  Woct [24,26)
//   q2     [26,34)  kv2 [34,42)  ctxbf [42,46)
//   VtCr   [16,20)   written after Wost/Wqt dead (post dual-GEMM)
//   hid    [16,48)   written after everything above is dead
//   W2t    [48,56)   ONLY if ws >= 56 MB (merged wconvert); else wbuf (serial)
extern "C" void kernel_launch(void* const* d_in, const int* in_sizes, int n_in,
                              void* d_out, int out_size, void* d_ws, size_t ws_size,
                              hipStream_t stream) {
  const float* x    = (const float*)d_in[0];
  const float* ctx  = (const float*)d_in[1];
  const float* Wqkv = (const float*)d_in[2];
  const float* bqkv = (const float*)d_in[3];
  const float* Wos  = (const float*)d_in[4];
  const float* bos  = (const float*)d_in[5];
  const float* Wq   = (const float*)d_in[6];
  const float* bq   = (const float*)d_in[7];
  const float* Wkv  = (const float*)d_in[8];
  const float* bkv  = (const float*)d_in[9];
  const float* Woc  = (const float*)d_in[10];
  const float* boc  = (const float*)d_in[11];
  const float* W1   = (const float*)d_in[12];
  const float* b1   = (const float*)d_in[13];
  const float* W2   = (const float*)d_in[14];
  const float* b2   = (const float*)d_in[15];
  float* out = (float*)d_out;
  char* ws = (char*)d_ws;
  const size_t MB = 1024 * 1024;
  const float SCL = 0.18033688f;   // log2(e) / sqrt(64)

  u16* h      = (u16*)ws;
  u16* abuf   = (u16*)(ws + 8 * MB);
  u16* wbuf   = (u16*)(ws + 8 * MB);
  u16* qkv    = (u16*)(ws + 16 * MB);
  u16* Wqkvt  = (u16*)(ws + 40 * MB);
  u16* Wost   = (u16*)(ws + 16 * MB);
  u16* Wqt    = (u16*)(ws + 18 * MB);
  u16* Wkvt   = (u16*)(ws + 20 * MB);
  u16* Woct   = (u16*)(ws + 24 * MB);
  u16* q2     = (u16*)(ws + 26 * MB);
  u16* kv2    = (u16*)(ws + 34 * MB);
  u16* ctxbf  = (u16*)(ws + 42 * MB);
  u16* VtCr   = (u16*)(ws + 16 * MB);
  u16* hid    = (u16*)(ws + 16 * MB);
  u16* VtSelf = h;
  u16* W1t    = wbuf;
  const bool bigWs = (ws_size >= 56 * MB);
  u16* W2t    = bigWs ? (u16*)(ws + 48 * MB) : wbuf;

  WEnts w1; w1.n = 1;

  // ---- self-attention branch: ln1 + wconvert(Wqkv) fused into one dispatch ----
  w1.e[0] = {Wqkv, Wqkvt, 1024, 3072, 768};
  ln_wconv_combo<<<dim3(4096 + 768), dim3(256), 0, stream>>>(x, h, 4096, w1);
  // qkv: TM=128/TN=64/BK=64 -> 1536 blocks = two clean rounds at 3 blk/CU (48KB LDS)
  gemm_bt<64, 2, true, false, false><<<dim3(1536), dim3(256), 0, stream>>>(
      h, Wqkvt, bqkv, nullptr, qkv, 3072, 1024, 24, 8, 1024, SCL);
  vtrans<<<dim3(32, 16, 2), dim3(256), 0, stream>>>(
      qkv + 2048, VtSelf, 3072, (long)2048 * 3072, 2048);
  attn_kernel<<<dim3(512), dim3(256), 0, stream>>>(
      qkv, qkv + 1024, VtSelf, abuf, 2048, 3072, 3072, 1024,
      (long)2048 * 3072, (long)2048 * 3072, (long)2048 * 1024);

  // ---- batched wconvert for next 4 GEMMs + f2bf(ctx), one dispatch ----
  WEnts w4; w4.n = 4;
  w4.e[0] = {Wos, Wost, 1024, 1024, 256};
  w4.e[1] = {Wq,  Wqt,  1024, 1024, 512};
  w4.e[2] = {Wkv, Wkvt, 1024, 2048, 1024};
  w4.e[3] = {Woc, Woct, 1024, 1024, 1280};
  wconv_f2bf_combo<<<dim3(1280 + 2048), dim3(256), 0, stream>>>(w4, 1280, ctx, ctxbf);

  // Wos: 32x16 = 512 blocks
  gemm_bt<64, 1, false, false, true><<<dim3(512), dim3(256), 0, stream>>>(
      abuf, Wost, bos, x, out, 1024, 1024, 16, 4, 0, 1.0f);
  ln_kernel<<<dim3(4096), dim3(256), 0, stream>>>(out, h);

  // ---- cross-attention branch: q2 and kv2 projections fused into one dispatch ----
  GemmDualP dp;
  dp.s0 = {h,     Wqt,  bq,  q2,  1024, 1024, 1, 16, 4, 1024, SCL};
  dp.s1 = {ctxbf, Wkvt, bkv, kv2, 2048, 1024, 2, 16, 4, 0, 1.0f};
  dp.nBlk0 = 512;
  gemm_dual<64><<<dim3(1024), dim3(256), 0, stream>>>(dp);
  vtrans<<<dim3(16, 16, 2), dim3(256), 0, stream>>>(
      kv2 + 1024, VtCr, 2048, (long)1024 * 2048, 1024);
  attn_kernel<<<dim3(512), dim3(256), 0, stream>>>(
      q2, kv2, VtCr, abuf, 1024, 1024, 2048, 1024,
      (long)2048 * 1024, (long)1024 * 2048, (long)2048 * 1024);
  gemm_bt<64, 1, false, false, true><<<dim3(512), dim3(256), 0, stream>>>(
      abuf, Woct, boc, out, out, 1024, 1024, 16, 4, 0, 1.0f);

  // ---- MLP ----
  if (bigWs) {
    // ln3 + wconvert(W1) + wconvert(W2) fused; W2t lives at [48,56) (free all MLP)
    WEnts w2c; w2c.n = 2;
    w2c.e[0] = {W1, W1t, 1024, 4096, 1024};
    w2c.e[1] = {W2, W2t, 4096, 1024, 2048};
    ln_wconv_combo<<<dim3(4096 + 2048), dim3(256), 0, stream>>>(out, h, 4096, w2c);
    gemm_bt<128, 2, true, true, false><<<dim3(1024), dim3(256), 0, stream>>>(
        h, W1t, b1, nullptr, hid, 4096, 1024, 16, 8, 0, 1.0f);
  } else {
    w1.e[0] = {W1, W1t, 1024, 4096, 1024};
    ln_wconv_combo<<<dim3(4096 + 1024), dim3(256), 0, stream>>>(out, h, 4096, w1);
    gemm_bt<128, 2, true, true, false><<<dim3(1024), dim3(256), 0, stream>>>(
        h, W1t, b1, nullptr, hid, 4096, 1024, 16, 8, 0, 1.0f);
    w1.e[0] = {W2, W2t, 4096, 1024, 1024};
    wconvert_all<<<dim3(1024), dim3(256), 0, stream>>>(w1);
  }
  // W2: R12/R14-proven config — TN=64, 512 blocks, BK=64 (49 µs measured)
  gemm_bt<64, 1, false, false, true><<<dim3(512), dim3(256), 0, stream>>>(
      hid, W2t, b2, out, out, 1024, 4096, 16, 4, 0, 1.0f);
}